// Round 1
// baseline (4273.875 us; speedup 1.0000x reference)
//
#include <hip/hip_runtime.h>
#include <math.h>

#define BB 1024
#define TT 50
#define FF 48
#define DD 512
#define EXTN 60
#define NFREQ 31

// ---------------- kernel 0: DCT-II matrix (orthonormal) + tail sums ----------------
__global__ void dctm_kernel(float* __restrict__ dctm, float* __restrict__ dtail) {
    int idx = blockIdx.x * blockDim.x + threadIdx.x;
    if (idx < 900) {
        int d = idx / 30, k = idx % 30;
        double w = (d == 0) ? sqrt(1.0 / 30.0) : sqrt(2.0 / 30.0);
        dctm[idx] = (float)(w * cos(M_PI * (k + 0.5) * d / 30.0));
    } else if (idx < 910) {
        int d = idx - 900;
        double w = (d == 0) ? sqrt(1.0 / 30.0) : sqrt(2.0 / 30.0);
        double s = 0.0;
        for (int k = 10; k < 30; ++k) s += w * cos(M_PI * (k + 0.5) * d / 30.0);
        dtail[d] = (float)s;
    }
}

// ---------------- kernel 1: dct_in[b,f,d] = sum_k dctm[d,k] * gcn_in[k,f] ----------------
// gcn_in[k] = seq[40+k] for k<10, seq[49] for k>=10 (tail folded into dtail)
__global__ void dct_in_kernel(const float* __restrict__ seq, const float* __restrict__ dctm,
                              const float* __restrict__ dtail, float* __restrict__ dct_in, int Bc) {
    int idx = blockIdx.x * blockDim.x + threadIdx.x;
    if (idx >= Bc * 480) return;
    int b = idx / 480, r = idx % 480;
    int f = r / 10, d = r % 10;
    const float* s = seq + (size_t)b * TT * FF;
    float acc = dtail[d] * s[49 * FF + f];
    #pragma unroll
    for (int k = 0; k < 10; ++k) acc += dctm[d * 30 + k] * s[(40 + k) * FF + f];
    dct_in[idx] = acc;
}

// ---------------- kernel 2: fused gconv: out = [resid +] [tanh]( att @ (X @ W) + bias ) ----------
// X: (B,48,K)  W: (K,N)  att: (48,48)  out: (B,48,N).  One WG = one batch x 128-col tile.
__launch_bounds__(192)
__global__ void gconv_kernel(const float* __restrict__ X, int K,
                             const float* __restrict__ W, int N,
                             const float* __restrict__ att,
                             const float* __restrict__ bias,
                             const float* __restrict__ resid,
                             float* __restrict__ out, int do_tanh) {
    __shared__ __align__(16) float smem[8496];
    float* XsT = smem;          // [16][52]  (transposed A tile, padded)
    float* Ws  = smem + 832;    // [16][128]
    float* Cs  = smem;          // [48][129] (epilogue, unions with XsT/Ws)
    float* As  = smem + 6192;   // [48][48]  (disjoint from GEMM-phase region)
    const int tid  = threadIdx.x;
    const int b    = blockIdx.y;
    const int c0   = blockIdx.x * 128;
    const int trow = tid >> 4;   // 0..11 -> rows trow*4..+3
    const int tcol = tid & 15;   // 0..15 -> cols tcol*8..+7

    // att load (region untouched during GEMM phase)
    for (int idx = tid; idx < 2304; idx += 192) As[idx] = att[idx];

    float acc[4][8];
    #pragma unroll
    for (int i = 0; i < 4; ++i)
        #pragma unroll
        for (int j = 0; j < 8; ++j) acc[i][j] = 0.f;

    const float* Xb = X + (size_t)b * 48 * K;
    for (int k0 = 0; k0 < K; k0 += 16) {
        for (int idx = tid; idx < 768; idx += 192) {
            int kk = idx & 15, m = idx >> 4;
            float v = 0.f;
            if (k0 + kk < K) v = Xb[m * K + k0 + kk];
            XsT[kk * 52 + m] = v;
        }
        for (int idx = tid; idx < 2048; idx += 192) {
            int r = idx >> 7, c = idx & 127;
            int gk = k0 + r, gc = c0 + c;
            float v = 0.f;
            if (gk < K && gc < N) v = W[(size_t)gk * N + gc];
            Ws[r * 128 + c] = v;
        }
        __syncthreads();
        #pragma unroll
        for (int kk = 0; kk < 16; ++kk) {
            float xv[4], wv[8];
            #pragma unroll
            for (int i = 0; i < 4; ++i) xv[i] = XsT[kk * 52 + trow * 4 + i];
            #pragma unroll
            for (int j = 0; j < 8; ++j) wv[j] = Ws[kk * 128 + tcol * 8 + j];
            #pragma unroll
            for (int i = 0; i < 4; ++i)
                #pragma unroll
                for (int j = 0; j < 8; ++j) acc[i][j] += xv[i] * wv[j];
        }
        __syncthreads();
    }
    // epilogue: C tile to LDS, then att-mix per column
    #pragma unroll
    for (int i = 0; i < 4; ++i)
        #pragma unroll
        for (int j = 0; j < 8; ++j)
            Cs[(trow * 4 + i) * 129 + tcol * 8 + j] = acc[i][j];
    __syncthreads();
    for (int idx = tid; idx < 6144; idx += 192) {
        int n = idx >> 7, c = idx & 127;
        int gc = c0 + c;
        if (gc < N) {
            float s = bias[gc];
            #pragma unroll
            for (int m = 0; m < 48; ++m) s += As[n * 48 + m] * Cs[m * 129 + c];
            if (do_tanh) s = tanhf(s);
            size_t o = ((size_t)b * 48 + n) * N + gc;
            if (resid) s += resid[o];
            out[o] = s;
        }
    }
}

// ---------------- kernel 3: recon[b,t,f] = sum_d dctm[d,t]*gcn_out[b,f,d] (idct = dctm^T) -------
__global__ void recon_kernel(const float* __restrict__ gcn_out, const float* __restrict__ dctm,
                             float* __restrict__ fused, int Bc) {
    int idx = blockIdx.x * blockDim.x + threadIdx.x;
    if (idx >= Bc * 1440) return;
    int b = idx / 1440, r = idx % 1440;
    int f = r / 30, t = r % 30;
    const float* g = gcn_out + ((size_t)b * 48 + f) * 10;
    float s = 0.f;
    #pragma unroll
    for (int d = 0; d < 10; ++d) s += dctm[d * 30 + t] * g[d];
    fused[(size_t)b * 1920 + f * 40 + t] = s;
}

// ---------------- kernel 4: FFC branch (direct DFT; only first 10 irfft samples needed) --------
__launch_bounds__(256)
__global__ void ffc_kernel(const float* __restrict__ seq, const float* __restrict__ wl,
                           const float* __restrict__ wg, float* __restrict__ fused) {
    int b = blockIdx.x, tid = threadIdx.x;
    __shared__ float ext[EXTN][FF];
    __shared__ float Xre[FF][32];
    __shared__ float Xim[FF][32];
    __shared__ float Yo[6][16][32];
    __shared__ float c60[60], s60[60];
    __shared__ float wls[9], wgs[36];
    const float* s = seq + (size_t)b * TT * FF;
    for (int idx = tid; idx < EXTN * FF; idx += 256) {
        int t = idx / FF, f = idx % FF;
        int ts = t < TT ? t : TT - 1;
        ext[t][f] = s[ts * FF + f];
    }
    if (tid < 60) { c60[tid] = cospif(tid / 30.0f); s60[tid] = sinpif(tid / 30.0f); }
    if (tid >= 64 && tid < 73) wls[tid - 64] = wl[tid - 64];
    if (tid >= 128 && tid < 164) wgs[tid - 128] = wg[tid - 128];
    __syncthreads();
    // rfft: X[k] = sum_t x[t] e^{-2pi i k t/60}
    for (int idx = tid; idx < FF * NFREQ; idx += 256) {
        int f = idx % FF, k = idx / FF;
        float re = 0.f, im = 0.f;
        int kt = 0;
        for (int t = 0; t < EXTN; ++t) {
            float v = ext[t][f];
            re += v * c60[kt];
            im -= v * s60[kt];
            kt += k; kt = (kt >= 60) ? kt - 60 : kt;
        }
        Xre[f][k] = re; Xim[f][k] = im;
    }
    __syncthreads();
    // channel mix (6x6) + relu, channels = [re0,re1,re2,im0,im1,im2]
    for (int idx = tid; idx < 6 * 16 * NFREQ; idx += 256) {
        int k = idx % NFREQ; int g = (idx / NFREQ) % 16; int o = idx / (NFREQ * 16);
        float v = wgs[o * 6 + 0] * Xre[g][k]      + wgs[o * 6 + 1] * Xre[16 + g][k]
                + wgs[o * 6 + 2] * Xre[32 + g][k] + wgs[o * 6 + 3] * Xim[g][k]
                + wgs[o * 6 + 4] * Xim[16 + g][k] + wgs[o * 6 + 5] * Xim[32 + g][k];
        Yo[o][g][k] = fmaxf(v, 0.f);
    }
    __syncthreads();
    // irfft (c2r: imag of bins 0,30 ignored), t<10 only, + local 3x3 mix
    for (int idx = tid; idx < 480; idx += 256) {
        int t = idx % 10; int g = (idx / 10) % 16; int c = idx / 160;
        float acc = Yo[c][g][0] + Yo[c][g][30] * ((t & 1) ? -1.f : 1.f);
        float s2 = 0.f;
        int kt = t;
        for (int k = 1; k < 30; ++k) {
            s2 += Yo[c][g][k] * c60[kt] - Yo[c + 3][g][k] * s60[kt];
            kt += t; kt = (kt >= 60) ? kt - 60 : kt;
        }
        acc = (acc + 2.f * s2) * (1.0f / 60.0f);
        float loc = wls[c * 3 + 0] * ext[t][g] + wls[c * 3 + 1] * ext[t][16 + g]
                  + wls[c * 3 + 2] * ext[t][32 + g];
        int f = c * 16 + g;
        fused[(size_t)b * 1920 + f * 40 + 30 + t] = acc + loc;
    }
}

// ---------------- kernel 5: MLP head (only first 10 of 40 output rows needed) ----------------
__launch_bounds__(256)
__global__ void mlp_kernel(const float* __restrict__ fused, const float* __restrict__ w1,
                           const float* __restrict__ w2, float* __restrict__ out) {
    int b = blockIdx.x, tid = threadIdx.x;
    __shared__ float fs[48][40];
    __shared__ float hs[48][257];
    for (int idx = tid; idx < 1920; idx += 256) fs[idx / 40][idx % 40] = fused[(size_t)b * 1920 + idx];
    __syncthreads();
    for (int idx = tid; idx < 48 * 256; idx += 256) {
        int o = idx & 255, f = idx >> 8;
        const float* wr = w1 + o * 40;
        float s = 0.f;
        #pragma unroll
        for (int t = 0; t < 40; ++t) s += fs[f][t] * wr[t];
        hs[f][o] = fmaxf(s, 0.f);
    }
    __syncthreads();
    for (int idx = tid; idx < 480; idx += 256) {
        int f = idx % 48, t = idx / 48;
        const float* wr = w2 + t * 256;
        float s = 0.f;
        for (int o = 0; o < 256; ++o) s += hs[f][o] * wr[o];
        out[(size_t)b * 480 + t * 48 + f] = s;
    }
}

extern "C" void kernel_launch(void* const* d_in, const int* in_sizes, int n_in,
                              void* d_out, int out_size, void* d_ws, size_t ws_size,
                              hipStream_t stream) {
    (void)in_sizes; (void)n_in; (void)out_size;
    const float* seq     = (const float*)d_in[0];
    // d_in[1..4] = wq1,wq2,wk1,wk2 — dead code (attention branch sliced away by combined[:,:,:10])
    const float* gc1_w   = (const float*)d_in[5];
    const float* gc1_att = (const float*)d_in[6];
    const float* gc1_b   = (const float*)d_in[7];
    const float* gcb_w   = (const float*)d_in[8];
    const float* gcb_att = (const float*)d_in[9];
    const float* gcb_b   = (const float*)d_in[10];
    const float* gc7_w   = (const float*)d_in[11];
    const float* gc7_att = (const float*)d_in[12];
    const float* gc7_b   = (const float*)d_in[13];
    const float* mlp_w1  = (const float*)d_in[14];
    const float* mlp_w2  = (const float*)d_in[15];
    const float* ffc_wl  = (const float*)d_in[16];
    const float* ffc_wg  = (const float*)d_in[17];
    float* out = (float*)d_out;
    float* ws  = (float*)d_ws;

    float* dctm  = ws;         // 900
    float* dtail = ws + 900;   // 10
    float* base  = ws + 1024;

    // per-batch scratch floats: dct_in 480 + gcn_out 480 + fused 1920 + Y 24576 + H 24576
    const size_t per_batch = 52032;
    size_t avail = ws_size / 4 - 1024;
    int nc = 1;
    while ((size_t)(BB / nc) * per_batch > avail && nc < 64) nc *= 2;
    int Bc = BB / nc;

    float* dct_in  = base;
    float* gcn_out = dct_in + (size_t)Bc * 480;
    float* fusedb  = gcn_out + (size_t)Bc * 480;
    float* Y       = fusedb + (size_t)Bc * 1920;
    float* H       = Y + (size_t)Bc * 24576;

    dctm_kernel<<<4, 256, 0, stream>>>(dctm, dtail);

    for (int ci = 0; ci < nc; ++ci) {
        const float* seqc = seq + (size_t)ci * Bc * TT * FF;
        float* outc = out + (size_t)ci * Bc * 480;
        int n1 = Bc * 480;
        dct_in_kernel<<<(n1 + 255) / 256, 256, 0, stream>>>(seqc, dctm, dtail, dct_in, Bc);
        dim3 g4(4, Bc), g1(1, Bc);
        // gc1: K=10 -> Y = tanh(att1 @ (dct_in @ W1) + b1)
        gconv_kernel<<<g4, 192, 0, stream>>>(dct_in, 10, gc1_w, 512, gc1_att, gc1_b, nullptr, Y, 1);
        // block 0
        gconv_kernel<<<g4, 192, 0, stream>>>(Y, 512, gcb_w + 0 * 262144, 512, gcb_att + 0 * 2304, gcb_b + 0 * 512, nullptr, H, 1);
        gconv_kernel<<<g4, 192, 0, stream>>>(H, 512, gcb_w + 1 * 262144, 512, gcb_att + 1 * 2304, gcb_b + 1 * 512, Y, Y, 1);
        // block 1
        gconv_kernel<<<g4, 192, 0, stream>>>(Y, 512, gcb_w + 2 * 262144, 512, gcb_att + 2 * 2304, gcb_b + 2 * 512, nullptr, H, 1);
        gconv_kernel<<<g4, 192, 0, stream>>>(H, 512, gcb_w + 3 * 262144, 512, gcb_att + 3 * 2304, gcb_b + 3 * 512, Y, Y, 1);
        // gc7: N=10, no tanh, residual = dct_in
        gconv_kernel<<<g1, 192, 0, stream>>>(Y, 512, gc7_w, 10, gc7_att, gc7_b, dct_in, gcn_out, 0);
        int n2 = Bc * 1440;
        recon_kernel<<<(n2 + 255) / 256, 256, 0, stream>>>(gcn_out, dctm, fusedb, Bc);
        ffc_kernel<<<Bc, 256, 0, stream>>>(seqc, ffc_wl, ffc_wg, fusedb);
        mlp_kernel<<<Bc, 256, 0, stream>>>(fusedb, mlp_w1, mlp_w2, outc);
    }
}

// Round 2
// 686.162 us; speedup vs baseline: 6.2287x; 6.2287x over previous
//
#include <hip/hip_runtime.h>
#include <math.h>

#define BB 1024
#define TT 50
#define FF 48
#define EXTN 60
#define NFREQ 31

typedef _Float16 h8 __attribute__((ext_vector_type(8)));
typedef _Float16 h4 __attribute__((ext_vector_type(4)));
typedef float f4 __attribute__((ext_vector_type(4)));

__device__ __forceinline__ float fast_tanh(float x) {
    float e = __expf(2.0f * x);
    return 1.0f - 2.0f * __builtin_amdgcn_rcpf(e + 1.0f);
}

// ---------------- kernel 0: DCT-II matrix (orthonormal) + tail sums ----------------
__global__ void dctm_kernel(float* __restrict__ dctm, float* __restrict__ dtail) {
    int idx = blockIdx.x * blockDim.x + threadIdx.x;
    if (idx < 900) {
        int d = idx / 30, k = idx % 30;
        double w = (d == 0) ? sqrt(1.0 / 30.0) : sqrt(2.0 / 30.0);
        dctm[idx] = (float)(w * cos(M_PI * (k + 0.5) * d / 30.0));
    } else if (idx < 910) {
        int d = idx - 900;
        double w = (d == 0) ? sqrt(1.0 / 30.0) : sqrt(2.0 / 30.0);
        double s = 0.0;
        for (int k = 10; k < 30; ++k) s += w * cos(M_PI * (k + 0.5) * d / 30.0);
        dtail[d] = (float)s;
    }
}

// ---------------- weight conversion: Wt[n][k] = (f16) W[k][n] ----------------
__global__ void cvt_w_kernel(const float* __restrict__ W, _Float16* __restrict__ Wt, int K, int N) {
    int idx = blockIdx.x * blockDim.x + threadIdx.x;
    if (idx >= N * K) return;
    int n = idx / K, k = idx % K;
    Wt[idx] = (_Float16)W[(size_t)k * N + n];
}

__global__ void cvt_copy_kernel(const float* __restrict__ src, _Float16* __restrict__ dst, int n) {
    int idx = blockIdx.x * blockDim.x + threadIdx.x;
    if (idx < n) dst[idx] = (_Float16)src[idx];
}

// ---------------- kernel 1: dct_in[b,f,d] = sum_k dctm[d,k] * gcn_in[k,f] ----------------
__global__ void dct_in_kernel(const float* __restrict__ seq, const float* __restrict__ dctm,
                              const float* __restrict__ dtail, float* __restrict__ dct_in,
                              _Float16* __restrict__ dct_in_h, int Bc) {
    int idx = blockIdx.x * blockDim.x + threadIdx.x;
    if (idx >= Bc * 480) return;
    int b = idx / 480, r = idx % 480;
    int f = r / 10, d = r % 10;
    const float* s = seq + (size_t)b * TT * FF;
    float acc = dtail[d] * s[49 * FF + f];
    #pragma unroll
    for (int k = 0; k < 10; ++k) acc += dctm[d * 30 + k] * s[(40 + k) * FF + f];
    dct_in[idx] = acc;
    dct_in_h[idx] = (_Float16)acc;
}

// ---------------- fused MFMA gconv: out = [resid +] [tanh]( att @ (A @ W) + bias ) ----------
// A: (B,48,K) f16.  Wt: (N,K) f16 (pre-transposed).  att_h: (48,48) f16.
// MODE 0: tanh, f16 out.  MODE 1: tanh + f16 resid, f16 out.  MODE 2: no tanh, fp32 resid/out (N=10).
#define PITCHB 144   // LDS row pitch in bytes (72 halves)

template<int MODE>
__launch_bounds__(256)
__global__ void gemm_att_kernel(const _Float16* __restrict__ A, int K,
                                const _Float16* __restrict__ Wt, int N,
                                const _Float16* __restrict__ att_h,
                                const float* __restrict__ bias,
                                const _Float16* __restrict__ residh,
                                const float* __restrict__ resid32,
                                _Float16* __restrict__ outh,
                                float* __restrict__ out32) {
    __shared__ __align__(16) char smem[32256];
    char* As  = smem;            // 48 x 72 halves
    char* Bs  = smem + 6912;     // 128 x 72 halves
    char* Ats = smem + 25344;    // 48 x 72 halves (att, padded to k=64 with zeros)
    char* Cs  = smem;            // 128 x 72 halves (epilogue, aliases As+Bs)

    const int tid  = threadIdx.x;
    const int b    = blockIdx.y;
    const int c0   = blockIdx.x * 128;
    const int wv   = tid >> 6;
    const int lane = tid & 63;
    const int l16  = lane & 15;
    const int quad = lane >> 4;
    const _Float16 HZ = (_Float16)0.0f;

    // stage att (48x48 -> 48x64, zero-padded)
    for (int v = tid; v < 384; v += 256) {
        int row = v >> 3, koff = (v & 7) * 8;
        h8 val = (h8)HZ;
        if (koff < 48) val = *(const h8*)(att_h + row * 48 + koff);
        *(h8*)(Ats + row * PITCHB + koff * 2) = val;
    }

    f4 acc[3][2];
    #pragma unroll
    for (int r = 0; r < 3; ++r)
        #pragma unroll
        for (int c = 0; c < 2; ++c) acc[r][c] = (f4)0.0f;

    const _Float16* Ab = A + (size_t)b * 48 * K;
    const bool al8 = (K & 7) == 0;

    for (int k0 = 0; k0 < K; k0 += 64) {
        const int Krem = K - k0;
        // stage A tile: 48 x 64 halves
        for (int v = tid; v < 384; v += 256) {
            int row = v >> 3, koff = (v & 7) * 8;
            h8 val = (h8)HZ;
            if (al8 && koff + 8 <= Krem) {
                val = *(const h8*)(Ab + (size_t)row * K + k0 + koff);
            } else {
                #pragma unroll
                for (int j = 0; j < 8; ++j)
                    if (koff + j < Krem) val[j] = Ab[(size_t)row * K + k0 + koff + j];
            }
            *(h8*)(As + row * PITCHB + koff * 2) = val;
        }
        // stage B tile: 128 x 64 halves (rows of Wt)
        for (int v = tid; v < 1024; v += 256) {
            int row = v >> 3, koff = (v & 7) * 8;
            h8 val = (h8)HZ;
            int gn = c0 + row;
            if (gn < N) {
                const _Float16* Wr = Wt + (size_t)gn * K + k0;
                if (al8 && koff + 8 <= Krem) {
                    val = *(const h8*)(Wr + koff);
                } else {
                    #pragma unroll
                    for (int j = 0; j < 8; ++j)
                        if (koff + j < Krem) val[j] = Wr[koff + j];
                }
            }
            *(h8*)(Bs + row * PITCHB + koff * 2) = val;
        }
        __syncthreads();
        #pragma unroll
        for (int ks = 0; ks < 2; ++ks) {
            const int ko = ks * 64 + quad * 16;  // byte offset within LDS row
            h8 af[3], bf[2];
            #pragma unroll
            for (int r = 0; r < 3; ++r) af[r] = *(h8*)(As + (16 * r + l16) * PITCHB + ko);
            #pragma unroll
            for (int c = 0; c < 2; ++c) bf[c] = *(h8*)(Bs + (wv * 32 + c * 16 + l16) * PITCHB + ko);
            #pragma unroll
            for (int r = 0; r < 3; ++r)
                #pragma unroll
                for (int c = 0; c < 2; ++c)
                    acc[r][c] = __builtin_amdgcn_mfma_f32_16x16x32_f16(af[r], bf[c], acc[r][c], 0, 0, 0);
        }
        __syncthreads();
    }

    // write C transposed to LDS as f16: Cs[n][m]
    #pragma unroll
    for (int r = 0; r < 3; ++r)
        #pragma unroll
        for (int c = 0; c < 2; ++c) {
            h4 hv;
            #pragma unroll
            for (int i = 0; i < 4; ++i) hv[i] = (_Float16)acc[r][c][i];
            int n = wv * 32 + c * 16 + l16;
            *(h4*)(Cs + n * PITCHB + (16 * r + quad * 4) * 2) = hv;
        }
    // zero the m=48..63 pad
    {
        int colz = tid >> 1, off = (tid & 1) * 16;
        *(h8*)(Cs + colz * PITCHB + 96 + off) = (h8)HZ;
    }
    __syncthreads();

    // mix: D2 = att @ C  (K = 48 padded to 64)
    f4 acc2[3][2];
    #pragma unroll
    for (int r = 0; r < 3; ++r)
        #pragma unroll
        for (int c = 0; c < 2; ++c) acc2[r][c] = (f4)0.0f;
    #pragma unroll
    for (int ks = 0; ks < 2; ++ks) {
        const int ko = ks * 64 + quad * 16;
        h8 af[3], bf[2];
        #pragma unroll
        for (int r = 0; r < 3; ++r) af[r] = *(h8*)(Ats + (16 * r + l16) * PITCHB + ko);
        #pragma unroll
        for (int c = 0; c < 2; ++c) bf[c] = *(h8*)(Cs + (wv * 32 + c * 16 + l16) * PITCHB + ko);
        #pragma unroll
        for (int r = 0; r < 3; ++r)
            #pragma unroll
            for (int c = 0; c < 2; ++c)
                acc2[r][c] = __builtin_amdgcn_mfma_f32_16x16x32_f16(af[r], bf[c], acc2[r][c], 0, 0, 0);
    }

    // epilogue: bias + [tanh] + [resid] + store
    #pragma unroll
    for (int r = 0; r < 3; ++r)
        #pragma unroll
        for (int c = 0; c < 2; ++c) {
            int gc = c0 + wv * 32 + c * 16 + l16;
            #pragma unroll
            for (int i = 0; i < 4; ++i) {
                int n = 16 * r + quad * 4 + i;
                if (MODE == 2) {
                    if (gc < N) {
                        size_t o = ((size_t)b * 48 + n) * (size_t)N + gc;
                        float v = acc2[r][c][i] + bias[gc] + resid32[o];
                        out32[o] = v;
                    }
                } else {
                    float v = fast_tanh(acc2[r][c][i] + bias[gc]);
                    size_t o = ((size_t)b * 48 + n) * (size_t)N + gc;
                    if (MODE == 1) v += (float)residh[o];
                    outh[o] = (_Float16)v;
                }
            }
        }
}

// ---------------- recon[b,t,f] = sum_d dctm[d,t]*gcn_out[b,f,d] (idct = dctm^T) -------
__global__ void recon_kernel(const float* __restrict__ gcn_out, const float* __restrict__ dctm,
                             float* __restrict__ fused, int Bc) {
    int idx = blockIdx.x * blockDim.x + threadIdx.x;
    if (idx >= Bc * 1440) return;
    int b = idx / 1440, r = idx % 1440;
    int f = r / 30, t = r % 30;
    const float* g = gcn_out + ((size_t)b * 48 + f) * 10;
    float s = 0.f;
    #pragma unroll
    for (int d = 0; d < 10; ++d) s += dctm[d * 30 + t] * g[d];
    fused[(size_t)b * 1920 + f * 40 + t] = s;
}

// ---------------- FFC branch (direct DFT; only first 10 irfft samples needed) --------
__launch_bounds__(256)
__global__ void ffc_kernel(const float* __restrict__ seq, const float* __restrict__ wl,
                           const float* __restrict__ wg, float* __restrict__ fused) {
    int b = blockIdx.x, tid = threadIdx.x;
    __shared__ float ext[EXTN][FF];
    __shared__ float Xre[FF][32];
    __shared__ float Xim[FF][32];
    __shared__ float Yo[6][16][32];
    __shared__ float c60[60], s60[60];
    __shared__ float wls[9], wgs[36];
    const float* s = seq + (size_t)b * TT * FF;
    for (int idx = tid; idx < EXTN * FF; idx += 256) {
        int t = idx / FF, f = idx % FF;
        int ts = t < TT ? t : TT - 1;
        ext[t][f] = s[ts * FF + f];
    }
    if (tid < 60) { c60[tid] = cospif(tid / 30.0f); s60[tid] = sinpif(tid / 30.0f); }
    if (tid >= 64 && tid < 73) wls[tid - 64] = wl[tid - 64];
    if (tid >= 128 && tid < 164) wgs[tid - 128] = wg[tid - 128];
    __syncthreads();
    for (int idx = tid; idx < FF * NFREQ; idx += 256) {
        int f = idx % FF, k = idx / FF;
        float re = 0.f, im = 0.f;
        int kt = 0;
        for (int t = 0; t < EXTN; ++t) {
            float v = ext[t][f];
            re += v * c60[kt];
            im -= v * s60[kt];
            kt += k; kt = (kt >= 60) ? kt - 60 : kt;
        }
        Xre[f][k] = re; Xim[f][k] = im;
    }
    __syncthreads();
    for (int idx = tid; idx < 6 * 16 * NFREQ; idx += 256) {
        int k = idx % NFREQ; int g = (idx / NFREQ) % 16; int o = idx / (NFREQ * 16);
        float v = wgs[o * 6 + 0] * Xre[g][k]      + wgs[o * 6 + 1] * Xre[16 + g][k]
                + wgs[o * 6 + 2] * Xre[32 + g][k] + wgs[o * 6 + 3] * Xim[g][k]
                + wgs[o * 6 + 4] * Xim[16 + g][k] + wgs[o * 6 + 5] * Xim[32 + g][k];
        Yo[o][g][k] = fmaxf(v, 0.f);
    }
    __syncthreads();
    for (int idx = tid; idx < 480; idx += 256) {
        int t = idx % 10; int g = (idx / 10) % 16; int c = idx / 160;
        float acc = Yo[c][g][0] + Yo[c][g][30] * ((t & 1) ? -1.f : 1.f);
        float s2 = 0.f;
        int kt = t;
        for (int k = 1; k < 30; ++k) {
            s2 += Yo[c][g][k] * c60[kt] - Yo[c + 3][g][k] * s60[kt];
            kt += t; kt = (kt >= 60) ? kt - 60 : kt;
        }
        acc = (acc + 2.f * s2) * (1.0f / 60.0f);
        float loc = wls[c * 3 + 0] * ext[t][g] + wls[c * 3 + 1] * ext[t][16 + g]
                  + wls[c * 3 + 2] * ext[t][32 + g];
        int f = c * 16 + g;
        fused[(size_t)b * 1920 + f * 40 + 30 + t] = acc + loc;
    }
}

// ---------------- MLP head (only first 10 of 40 output rows needed) ----------------
__launch_bounds__(256)
__global__ void mlp_kernel(const float* __restrict__ fused, const float* __restrict__ w1,
                           const float* __restrict__ w2, float* __restrict__ out) {
    int b = blockIdx.x, tid = threadIdx.x;
    __shared__ float fs[48][40];
    __shared__ float hs[48][257];
    for (int idx = tid; idx < 1920; idx += 256) fs[idx / 40][idx % 40] = fused[(size_t)b * 1920 + idx];
    __syncthreads();
    for (int idx = tid; idx < 48 * 256; idx += 256) {
        int o = idx & 255, f = idx >> 8;
        const float* wr = w1 + o * 40;
        float s = 0.f;
        #pragma unroll
        for (int t = 0; t < 40; ++t) s += fs[f][t] * wr[t];
        hs[f][o] = fmaxf(s, 0.f);
    }
    __syncthreads();
    for (int idx = tid; idx < 480; idx += 256) {
        int f = idx % 48, t = idx / 48;
        const float* wr = w2 + t * 256;
        float s = 0.f;
        for (int o = 0; o < 256; ++o) s += hs[f][o] * wr[o];
        out[(size_t)b * 480 + t * 48 + f] = s;
    }
}

extern "C" void kernel_launch(void* const* d_in, const int* in_sizes, int n_in,
                              void* d_out, int out_size, void* d_ws, size_t ws_size,
                              hipStream_t stream) {
    (void)in_sizes; (void)n_in; (void)out_size;
    const float* seq     = (const float*)d_in[0];
    // d_in[1..4] = wq1,wq2,wk1,wk2 — dead (attention branch sliced away by combined[:,:,:10])
    const float* gc1_w   = (const float*)d_in[5];
    const float* gc1_att = (const float*)d_in[6];
    const float* gc1_b   = (const float*)d_in[7];
    const float* gcb_w   = (const float*)d_in[8];
    const float* gcb_att = (const float*)d_in[9];
    const float* gcb_b   = (const float*)d_in[10];
    const float* gc7_w   = (const float*)d_in[11];
    const float* gc7_att = (const float*)d_in[12];
    const float* gc7_b   = (const float*)d_in[13];
    const float* mlp_w1  = (const float*)d_in[14];
    const float* mlp_w2  = (const float*)d_in[15];
    const float* ffc_wl  = (const float*)d_in[16];
    const float* ffc_wg  = (const float*)d_in[17];
    float* out = (float*)d_out;
    char* ws = (char*)d_ws;

    // fixed region
    float*    dctm  = (float*)ws;                       // 900
    float*    dtail = dctm + 900;                       // 10
    _Float16* wt_h  = (_Float16*)(ws + 4096);           // 1,058,816 halves
    _Float16* att_h = (_Float16*)(ws + 4096 + 2117632); // 13,824 halves
    const size_t fixed_bytes = 4096 + 2117632 + 27648;

    _Float16* Wt1  = wt_h;                 // (512,10)
    _Float16* Wtb  = wt_h + 5120;          // 4 x (512,512)
    _Float16* Wt7  = wt_h + 5120 + 4 * 262144; // (10,512)
    _Float16* att1 = att_h;                // 2304
    _Float16* attb = att_h + 2304;         // 4 x 2304
    _Float16* att7 = att_h + 2304 + 9216;  // 2304

    // per-batch scratch: dct_in 1920B + gcn_out 1920B + fused 7680B + dct_in_h 960B + Y 49152B + H 49152B
    const size_t per_batch = 110784;
    size_t avail = (ws_size > fixed_bytes) ? (ws_size - fixed_bytes) : 0;
    int nc = 1;
    while ((size_t)(BB / nc) * per_batch > avail && nc < 64) nc *= 2;
    int Bc = BB / nc;

    char* p = ws + fixed_bytes;
    float*    dct_in   = (float*)p;                 p += (size_t)Bc * 1920;
    float*    gcn_out  = (float*)p;                 p += (size_t)Bc * 1920;
    float*    fusedb   = (float*)p;                 p += (size_t)Bc * 7680;
    _Float16* dct_in_h = (_Float16*)p;              p += (size_t)Bc * 960;
    _Float16* Y        = (_Float16*)p;              p += (size_t)Bc * 49152;
    _Float16* H        = (_Float16*)p;

    dctm_kernel<<<4, 256, 0, stream>>>(dctm, dtail);
    // weight conversions (once per call)
    cvt_w_kernel<<<20, 256, 0, stream>>>(gc1_w, Wt1, 10, 512);
    for (int s = 0; s < 4; ++s)
        cvt_w_kernel<<<1024, 256, 0, stream>>>(gcb_w + (size_t)s * 262144, Wtb + (size_t)s * 262144, 512, 512);
    cvt_w_kernel<<<20, 256, 0, stream>>>(gc7_w, Wt7, 512, 10);
    cvt_copy_kernel<<<9, 256, 0, stream>>>(gc1_att, att1, 2304);
    cvt_copy_kernel<<<36, 256, 0, stream>>>(gcb_att, attb, 9216);
    cvt_copy_kernel<<<9, 256, 0, stream>>>(gc7_att, att7, 2304);

    for (int ci = 0; ci < nc; ++ci) {
        const float* seqc = seq + (size_t)ci * Bc * TT * FF;
        float* outc = out + (size_t)ci * Bc * 480;
        int n1 = Bc * 480;
        dct_in_kernel<<<(n1 + 255) / 256, 256, 0, stream>>>(seqc, dctm, dtail, dct_in, dct_in_h, Bc);
        dim3 g4(4, Bc), g1(1, Bc);
        // L1: Y = tanh(att1 @ (dct_in @ W1) + b1), K=10
        gemm_att_kernel<0><<<g4, 256, 0, stream>>>(dct_in_h, 10, Wt1, 512, att1, gc1_b, nullptr, nullptr, Y, nullptr);
        // L2: H = tanh(att2 @ (Y @ W2) + b2)
        gemm_att_kernel<0><<<g4, 256, 0, stream>>>(Y, 512, Wtb + 0 * 262144, 512, attb + 0 * 2304, gcb_b + 0 * 512, nullptr, nullptr, H, nullptr);
        // L3: Y = Y + tanh(att3 @ (H @ W3) + b3)
        gemm_att_kernel<1><<<g4, 256, 0, stream>>>(H, 512, Wtb + 1 * 262144, 512, attb + 1 * 2304, gcb_b + 1 * 512, Y, nullptr, Y, nullptr);
        // L4: H = tanh(att4 @ (Y @ W4) + b4)
        gemm_att_kernel<0><<<g4, 256, 0, stream>>>(Y, 512, Wtb + 2 * 262144, 512, attb + 2 * 2304, gcb_b + 2 * 512, nullptr, nullptr, H, nullptr);
        // L5: Y = Y + tanh(att5 @ (H @ W5) + b5)
        gemm_att_kernel<1><<<g4, 256, 0, stream>>>(H, 512, Wtb + 3 * 262144, 512, attb + 3 * 2304, gcb_b + 3 * 512, Y, nullptr, Y, nullptr);
        // L6 (gc7): gcn_out = att7 @ (Y @ W7) + b7 + dct_in, N=10, fp32 out
        gemm_att_kernel<2><<<g1, 256, 0, stream>>>(Y, 512, Wt7, 10, att7, gc7_b, nullptr, dct_in, nullptr, gcn_out);
        int n2 = Bc * 1440;
        recon_kernel<<<(n2 + 255) / 256, 256, 0, stream>>>(gcn_out, dctm, fusedb, Bc);
        ffc_kernel<<<Bc, 256, 0, stream>>>(seqc, ffc_wl, ffc_wg, fusedb);
        mlp_kernel<<<Bc, 256, 0, stream>>>(fusedb, mlp_w1, mlp_w2, outc);
    }
}

// Round 3
// 470.800 us; speedup vs baseline: 9.0779x; 1.4574x over previous
//
#include <hip/hip_runtime.h>
#include <math.h>

#define BB 1024
#define TT 50
#define FF 48
#define EXTN 60
#define NFREQ 31

typedef _Float16 h8 __attribute__((ext_vector_type(8)));
typedef _Float16 h4 __attribute__((ext_vector_type(4)));
typedef float f4 __attribute__((ext_vector_type(4)));

__device__ __forceinline__ float fast_tanh(float x) {
    float e = __expf(2.0f * x);
    return 1.0f - 2.0f * __builtin_amdgcn_rcpf(e + 1.0f);
}

// async global->LDS, 16B per lane. LDS dest = wave-uniform base + lane*16.
__device__ __forceinline__ void gl16(const void* g, void* l) {
#if __has_builtin(__builtin_amdgcn_global_load_lds)
    __builtin_amdgcn_global_load_lds(
        (const __attribute__((address_space(1))) void*)(uintptr_t)g,
        (__attribute__((address_space(3))) void*)(uint32_t)(uintptr_t)l,
        16, 0, 0);
#else
    int lane = threadIdx.x & 63;
    *(h8*)((char*)l + lane * 16) = *(const h8*)g;
#endif
}

// ---------------- DCT-II matrix (orthonormal) + tail sums ----------------
__global__ void dctm_kernel(float* __restrict__ dctm, float* __restrict__ dtail) {
    int idx = blockIdx.x * blockDim.x + threadIdx.x;
    if (idx < 900) {
        int d = idx / 30, k = idx % 30;
        double w = (d == 0) ? sqrt(1.0 / 30.0) : sqrt(2.0 / 30.0);
        dctm[idx] = (float)(w * cos(M_PI * (k + 0.5) * d / 30.0));
    } else if (idx < 910) {
        int d = idx - 900;
        double w = (d == 0) ? sqrt(1.0 / 30.0) : sqrt(2.0 / 30.0);
        double s = 0.0;
        for (int k = 10; k < 30; ++k) s += w * cos(M_PI * (k + 0.5) * d / 30.0);
        dtail[d] = (float)s;
    }
}

// ---------------- LDS-tiled transpose+convert: Wt[n][k] = (f16) W[k][n], 512x512 x4 ----------------
__global__ void transp_kernel(const float* __restrict__ W, _Float16* __restrict__ Wt) {
    __shared__ _Float16 t[64][72];
    const float* Ws = W + (size_t)blockIdx.z * 262144;
    _Float16* Wd = Wt + (size_t)blockIdx.z * 262144;
    int k0 = blockIdx.y * 64, n0 = blockIdx.x * 64;
    int tid = threadIdx.x;
    for (int i = tid; i < 4096; i += 256) {
        int r = i >> 6, c = i & 63;
        t[r][c] = (_Float16)Ws[(size_t)(k0 + r) * 512 + n0 + c];
    }
    __syncthreads();
    for (int i = tid; i < 4096; i += 256) {
        int r = i >> 6, c = i & 63;
        Wd[(size_t)(n0 + r) * 512 + k0 + c] = t[c][r];
    }
}

// Wt1p[n][k] (512 x 64, zero-padded k>=10) from gc1_w (10,512)
__global__ void cvt_w1_kernel(const float* __restrict__ W, _Float16* __restrict__ Wt) {
    int idx = blockIdx.x * blockDim.x + threadIdx.x;
    if (idx >= 32768) return;
    int n = idx >> 6, k = idx & 63;
    Wt[idx] = (k < 10) ? (_Float16)W[k * 512 + n] : (_Float16)0.0f;
}

// Wt7p[n][k] (256 x 512, zero-padded n>=10) from gc7_w (512,10)
__global__ void cvt_w7_kernel(const float* __restrict__ W, _Float16* __restrict__ Wt) {
    int idx = blockIdx.x * blockDim.x + threadIdx.x;
    if (idx >= 131072) return;
    int n = idx >> 9, k = idx & 511;
    Wt[idx] = (n < 10) ? (_Float16)W[k * 10 + n] : (_Float16)0.0f;
}

__global__ void cvt_copy_kernel(const float* __restrict__ src, _Float16* __restrict__ dst, int n) {
    int idx = blockIdx.x * blockDim.x + threadIdx.x;
    if (idx < n) dst[idx] = (_Float16)src[idx];
}

// ---------------- dct_in[b,f,d] = sum_k dctm[d,k]*gcn_in[k,f]; f16 copy padded to 64 ----------------
__global__ void dct_in_kernel(const float* __restrict__ seq, const float* __restrict__ dctm,
                              const float* __restrict__ dtail, float* __restrict__ dct_in,
                              _Float16* __restrict__ dct_in_h, int Bc) {
    int idx = blockIdx.x * blockDim.x + threadIdx.x;
    if (idx >= Bc * 3072) return;
    int b = idx / 3072, r = idx % 3072;
    int f = r >> 6, d = r & 63;
    float acc = 0.f;
    if (d < 10) {
        const float* s = seq + (size_t)b * TT * FF;
        acc = dtail[d] * s[49 * FF + f];
        #pragma unroll
        for (int k = 0; k < 10; ++k) acc += dctm[d * 30 + k] * s[(40 + k) * FF + f];
        dct_in[(size_t)b * 480 + f * 10 + d] = acc;
    }
    dct_in_h[idx] = (_Float16)acc;
}

// ---------------- fused MFMA gconv: out = [resid +] [tanh]( att @ (A @ W) + bias ) ----------
// Tile: M=96 (2 batches) x N=256, K-chunk 64, 256 threads (4 waves), wave n-slice 64.
// A (rows of 2 batches, stride LDA) and Wt (N,KTOT) staged via global_load_lds with XOR
// source-block swizzle so contiguous LDS rows (128B) read conflict-free as MFMA fragments.
// MODE 0: tanh, f16 out. MODE 1: tanh + f16 resid. MODE 2: no tanh, fp32 resid/out, col guard.
template<int KTOT, int LDA, int MODE>
__launch_bounds__(256, 2)
__global__ void gemm3_kernel(const _Float16* __restrict__ A,
                             const _Float16* __restrict__ Wt,
                             const _Float16* __restrict__ att_h,
                             const float* __restrict__ bias,
                             const _Float16* __restrict__ residh,
                             const float* __restrict__ resid32,
                             _Float16* __restrict__ outh,
                             float* __restrict__ out32,
                             int NOUT) {
    __shared__ __align__(16) char smem[51968];
    char* As  = smem;               // 96 x 128 B  (swizzled blocks)
    char* Bs  = smem + 12288;       // 256 x 128 B (swizzled blocks)
    char* Cs  = smem;               // 256 x 144 B epilogue transit (aliases As+Bs)
    char* Ats = smem + 45056;       // 48 x 144 B att (k zero-padded to 64)

    const int tid  = threadIdx.x;
    const int lane = tid & 63, wv = tid >> 6;
    const int l16  = lane & 15, quad = lane >> 4;
    const int py   = blockIdx.y;
    const int c0   = blockIdx.x << 8;
    const _Float16 HZ = (_Float16)0.0f;

    // stage att (48 rows x 9 blocks of 16B, blocks >=6 zero)
    for (int v = tid; v < 432; v += 256) {
        int row = v / 9, blk = v % 9;
        h8 val = (h8)HZ;
        if (blk < 6) val = *(const h8*)(att_h + row * 48 + blk * 8);
        *(h8*)(Ats + row * 144 + blk * 16) = val;
    }

    // per-lane staging pointers (source-block XOR swizzle: lblk = (lane&7) ^ (lane>>3))
    const int lrow8 = lane >> 3;
    const int lblk  = (lane & 7) ^ lrow8;
    const char* aptr[3]; char* alds[3];
    #pragma unroll
    for (int j = 0; j < 3; ++j) {
        int row = (wv * 3 + j) * 8 + lrow8;                 // 0..95
        aptr[j] = (const char*)(A + (size_t)(py * 96 + row) * LDA + lblk * 8);
        alds[j] = As + (wv * 3 + j) * 1024;
    }
    const char* bptr[8]; char* blds[8];
    #pragma unroll
    for (int j = 0; j < 8; ++j) {
        int row = (wv * 8 + j) * 8 + lrow8;                 // 0..255
        bptr[j] = (const char*)(Wt + (size_t)(c0 + row) * KTOT + lblk * 8);
        blds[j] = Bs + (wv * 8 + j) * 1024;
    }

    f4 acc[6][4];
    #pragma unroll
    for (int r = 0; r < 6; ++r)
        #pragma unroll
        for (int ct = 0; ct < 4; ++ct) acc[r][ct] = (f4)0.0f;

    for (int k0 = 0; k0 < KTOT; k0 += 64) {
        #pragma unroll
        for (int j = 0; j < 3; ++j) { gl16(aptr[j], alds[j]); aptr[j] += 128; }
        #pragma unroll
        for (int j = 0; j < 8; ++j) { gl16(bptr[j], blds[j]); bptr[j] += 128; }
        __syncthreads();
        #pragma unroll
        for (int ks = 0; ks < 2; ++ks) {
            const int sw = (((ks * 4 + quad) ^ (l16 & 7)) << 4);
            h8 af[6], bf[4];
            #pragma unroll
            for (int r = 0; r < 6; ++r) af[r] = *(h8*)(As + (16 * r + l16) * 128 + sw);
            #pragma unroll
            for (int ct = 0; ct < 4; ++ct) bf[ct] = *(h8*)(Bs + (wv * 64 + ct * 16 + l16) * 128 + sw);
            #pragma unroll
            for (int r = 0; r < 6; ++r)
                #pragma unroll
                for (int ct = 0; ct < 4; ++ct)
                    acc[r][ct] = __builtin_amdgcn_mfma_f32_16x16x32_f16(af[r], bf[ct], acc[r][ct], 0, 0, 0);
        }
        __syncthreads();
    }

    // zero the k=48..63 pad of Cs (one 144B row per thread)
    *(h8*)(Cs + tid * 144 + 96)  = (h8)HZ;
    *(h8*)(Cs + tid * 144 + 112) = (h8)HZ;

    // two passes: batch bb in {0,1}
    #pragma unroll
    for (int bb = 0; bb < 2; ++bb) {
        // write C_b (48 x 256) transposed to Cs[c][m] as f16
        #pragma unroll
        for (int r = 0; r < 3; ++r)
            #pragma unroll
            for (int ct = 0; ct < 4; ++ct) {
                h4 hv;
                #pragma unroll
                for (int i = 0; i < 4; ++i) hv[i] = (_Float16)acc[3 * bb + r][ct][i];
                int ccol = wv * 64 + ct * 16 + l16;
                *(h4*)(Cs + ccol * 144 + (16 * r + quad * 4) * 2) = hv;
            }
        __syncthreads();
        // mix: D2 = att @ C_b
        f4 acc2[3][4];
        #pragma unroll
        for (int r = 0; r < 3; ++r)
            #pragma unroll
            for (int ct = 0; ct < 4; ++ct) acc2[r][ct] = (f4)0.0f;
        #pragma unroll
        for (int ks = 0; ks < 2; ++ks) {
            const int ko = ks * 64 + quad * 16;
            h8 af2[3], bf2[4];
            #pragma unroll
            for (int r = 0; r < 3; ++r) af2[r] = *(h8*)(Ats + (16 * r + l16) * 144 + ko);
            #pragma unroll
            for (int ct = 0; ct < 4; ++ct) bf2[ct] = *(h8*)(Cs + (wv * 64 + ct * 16 + l16) * 144 + ko);
            #pragma unroll
            for (int r = 0; r < 3; ++r)
                #pragma unroll
                for (int ct = 0; ct < 4; ++ct)
                    acc2[r][ct] = __builtin_amdgcn_mfma_f32_16x16x32_f16(af2[r], bf2[ct], acc2[r][ct], 0, 0, 0);
        }
        // epilogue store
        const int b = py * 2 + bb;
        #pragma unroll
        for (int ct = 0; ct < 4; ++ct) {
            int gc = c0 + wv * 64 + ct * 16 + l16;
            float bv = (MODE == 2) ? ((gc < NOUT) ? bias[gc] : 0.f) : bias[gc];
            #pragma unroll
            for (int r = 0; r < 3; ++r)
                #pragma unroll
                for (int i = 0; i < 4; ++i) {
                    int n = 16 * r + quad * 4 + i;
                    float v = acc2[r][ct][i] + bv;
                    if (MODE == 2) {
                        if (gc < NOUT) {
                            size_t o = ((size_t)b * 48 + n) * NOUT + gc;
                            out32[o] = v + resid32[o];
                        }
                    } else {
                        v = fast_tanh(v);
                        size_t o = ((size_t)b * 48 + n) * 512 + gc;
                        if (MODE == 1) v += (float)residh[o];
                        outh[o] = (_Float16)v;
                    }
                }
        }
        if (bb == 0) __syncthreads();   // protect Cs before pass-1 overwrite
    }
}

// ---------------- recon[b,t,f] = sum_d dctm[d,t]*gcn_out[b,f,d] (idct = dctm^T) -------
__global__ void recon_kernel(const float* __restrict__ gcn_out, const float* __restrict__ dctm,
                             float* __restrict__ fused, int Bc) {
    int idx = blockIdx.x * blockDim.x + threadIdx.x;
    if (idx >= Bc * 1440) return;
    int b = idx / 1440, r = idx % 1440;
    int f = r / 30, t = r % 30;
    const float* g = gcn_out + ((size_t)b * 48 + f) * 10;
    float s = 0.f;
    #pragma unroll
    for (int d = 0; d < 10; ++d) s += dctm[d * 30 + t] * g[d];
    fused[(size_t)b * 1920 + f * 40 + t] = s;
}

// ---------------- FFC branch (direct DFT; only first 10 irfft samples needed) --------
__launch_bounds__(256)
__global__ void ffc_kernel(const float* __restrict__ seq, const float* __restrict__ wl,
                           const float* __restrict__ wg, float* __restrict__ fused) {
    int b = blockIdx.x, tid = threadIdx.x;
    __shared__ float ext[EXTN][FF];
    __shared__ float Xre[FF][32];
    __shared__ float Xim[FF][32];
    __shared__ float Yo[6][16][32];
    __shared__ float c60[60], s60[60];
    __shared__ float wls[9], wgs[36];
    const float* s = seq + (size_t)b * TT * FF;
    for (int idx = tid; idx < EXTN * FF; idx += 256) {
        int t = idx / FF, f = idx % FF;
        int ts = t < TT ? t : TT - 1;
        ext[t][f] = s[ts * FF + f];
    }
    if (tid < 60) { c60[tid] = cospif(tid / 30.0f); s60[tid] = sinpif(tid / 30.0f); }
    if (tid >= 64 && tid < 73) wls[tid - 64] = wl[tid - 64];
    if (tid >= 128 && tid < 164) wgs[tid - 128] = wg[tid - 128];
    __syncthreads();
    for (int idx = tid; idx < FF * NFREQ; idx += 256) {
        int f = idx % FF, k = idx / FF;
        float re = 0.f, im = 0.f;
        int kt = 0;
        for (int t = 0; t < EXTN; ++t) {
            float v = ext[t][f];
            re += v * c60[kt];
            im -= v * s60[kt];
            kt += k; kt = (kt >= 60) ? kt - 60 : kt;
        }
        Xre[f][k] = re; Xim[f][k] = im;
    }
    __syncthreads();
    for (int idx = tid; idx < 6 * 16 * NFREQ; idx += 256) {
        int k = idx % NFREQ; int g = (idx / NFREQ) % 16; int o = idx / (NFREQ * 16);
        float v = wgs[o * 6 + 0] * Xre[g][k]      + wgs[o * 6 + 1] * Xre[16 + g][k]
                + wgs[o * 6 + 2] * Xre[32 + g][k] + wgs[o * 6 + 3] * Xim[g][k]
                + wgs[o * 6 + 4] * Xim[16 + g][k] + wgs[o * 6 + 5] * Xim[32 + g][k];
        Yo[o][g][k] = fmaxf(v, 0.f);
    }
    __syncthreads();
    for (int idx = tid; idx < 480; idx += 256) {
        int t = idx % 10; int g = (idx / 10) % 16; int c = idx / 160;
        float acc = Yo[c][g][0] + Yo[c][g][30] * ((t & 1) ? -1.f : 1.f);
        float s2 = 0.f;
        int kt = t;
        for (int k = 1; k < 30; ++k) {
            s2 += Yo[c][g][k] * c60[kt] - Yo[c + 3][g][k] * s60[kt];
            kt += t; kt = (kt >= 60) ? kt - 60 : kt;
        }
        acc = (acc + 2.f * s2) * (1.0f / 60.0f);
        float loc = wls[c * 3 + 0] * ext[t][g] + wls[c * 3 + 1] * ext[t][16 + g]
                  + wls[c * 3 + 2] * ext[t][32 + g];
        int f = c * 16 + g;
        fused[(size_t)b * 1920 + f * 40 + 30 + t] = acc + loc;
    }
}

// ---------------- MLP head (only first 10 of 40 output rows needed) ----------------
__launch_bounds__(256)
__global__ void mlp_kernel(const float* __restrict__ fused, const float* __restrict__ w1,
                           const float* __restrict__ w2, float* __restrict__ out) {
    int b = blockIdx.x, tid = threadIdx.x;
    __shared__ float fs[48][40];
    __shared__ float hs[48][257];
    for (int idx = tid; idx < 1920; idx += 256) fs[idx / 40][idx % 40] = fused[(size_t)b * 1920 + idx];
    __syncthreads();
    for (int idx = tid; idx < 48 * 256; idx += 256) {
        int o = idx & 255, f = idx >> 8;
        const float* wr = w1 + o * 40;
        float s = 0.f;
        #pragma unroll
        for (int t = 0; t < 40; ++t) s += fs[f][t] * wr[t];
        hs[f][o] = fmaxf(s, 0.f);
    }
    __syncthreads();
    for (int idx = tid; idx < 480; idx += 256) {
        int f = idx % 48, t = idx / 48;
        const float* wr = w2 + t * 256;
        float s = 0.f;
        for (int o = 0; o < 256; ++o) s += hs[f][o] * wr[o];
        out[(size_t)b * 480 + t * 48 + f] = s;
    }
}

extern "C" void kernel_launch(void* const* d_in, const int* in_sizes, int n_in,
                              void* d_out, int out_size, void* d_ws, size_t ws_size,
                              hipStream_t stream) {
    (void)in_sizes; (void)n_in; (void)out_size;
    const float* seq     = (const float*)d_in[0];
    // d_in[1..4] = wq1,wq2,wk1,wk2 — dead (attention branch sliced away by combined[:,:,:10])
    const float* gc1_w   = (const float*)d_in[5];
    const float* gc1_att = (const float*)d_in[6];
    const float* gc1_b   = (const float*)d_in[7];
    const float* gcb_w   = (const float*)d_in[8];
    const float* gcb_att = (const float*)d_in[9];
    const float* gcb_b   = (const float*)d_in[10];
    const float* gc7_w   = (const float*)d_in[11];
    const float* gc7_att = (const float*)d_in[12];
    const float* gc7_b   = (const float*)d_in[13];
    const float* mlp_w1  = (const float*)d_in[14];
    const float* mlp_w2  = (const float*)d_in[15];
    const float* ffc_wl  = (const float*)d_in[16];
    const float* ffc_wg  = (const float*)d_in[17];
    float* out = (float*)d_out;
    char* ws = (char*)d_ws;

    // fixed region
    float*    dctm  = (float*)ws;                        // 900 f
    float*    dtail = dctm + 900;                        // 10 f
    char*     p0    = ws + 4096;
    _Float16* Wtb   = (_Float16*)p0;           p0 += 4 * 262144 * 2;   // 4 x (512,512)
    _Float16* Wt1p  = (_Float16*)p0;           p0 += 32768 * 2;        // (512,64) zero-padded
    _Float16* Wt7p  = (_Float16*)p0;           p0 += 131072 * 2;       // (256,512) zero-padded
    _Float16* att1  = (_Float16*)p0;           p0 += 2304 * 2;
    _Float16* attb  = (_Float16*)p0;           p0 += 4 * 2304 * 2;
    _Float16* att7  = (_Float16*)p0;           p0 += 2304 * 2;
    const size_t fixed_bytes = (size_t)(p0 - ws);

    // per-batch scratch bytes: dct_in 1920 + gcn_out 1920 + fused 7680 + dct_in_h 6144 + Y 49152 + H 49152
    const size_t per_batch = 115968;
    size_t avail = (ws_size > fixed_bytes) ? (ws_size - fixed_bytes) : 0;
    int nc = 1;
    while ((size_t)(BB / nc) * per_batch > avail && nc < 64) nc *= 2;
    int Bc = BB / nc;

    char* p = ws + fixed_bytes;
    float*    dct_in   = (float*)p;                 p += (size_t)Bc * 1920;
    float*    gcn_out  = (float*)p;                 p += (size_t)Bc * 1920;
    float*    fusedb   = (float*)p;                 p += (size_t)Bc * 7680;
    _Float16* dct_in_h = (_Float16*)p;              p += (size_t)Bc * 6144;
    _Float16* Y        = (_Float16*)p;              p += (size_t)Bc * 49152;
    _Float16* H        = (_Float16*)p;

    dctm_kernel<<<4, 256, 0, stream>>>(dctm, dtail);
    transp_kernel<<<dim3(8, 8, 4), 256, 0, stream>>>(gcb_w, Wtb);
    cvt_w1_kernel<<<128, 256, 0, stream>>>(gc1_w, Wt1p);
    cvt_w7_kernel<<<512, 256, 0, stream>>>(gc7_w, Wt7p);
    cvt_copy_kernel<<<9, 256, 0, stream>>>(gc1_att, att1, 2304);
    cvt_copy_kernel<<<36, 256, 0, stream>>>(gcb_att, attb, 9216);
    cvt_copy_kernel<<<9, 256, 0, stream>>>(gc7_att, att7, 2304);

    for (int ci = 0; ci < nc; ++ci) {
        const float* seqc = seq + (size_t)ci * Bc * TT * FF;
        float* outc = out + (size_t)ci * Bc * 480;
        int n1 = Bc * 3072;
        dct_in_kernel<<<(n1 + 255) / 256, 256, 0, stream>>>(seqc, dctm, dtail, dct_in, dct_in_h, Bc);
        dim3 g2(2, Bc / 2), g1(1, Bc / 2);
        // L1: Y = tanh(att1 @ (dct_in @ W1) + b1), K padded to 64
        gemm3_kernel<64, 64, 0><<<g2, 256, 0, stream>>>(dct_in_h, Wt1p, att1, gc1_b, nullptr, nullptr, Y, nullptr, 512);
        // L2: H = tanh(att2 @ (Y @ W2) + b2)
        gemm3_kernel<512, 512, 0><<<g2, 256, 0, stream>>>(Y, Wtb + 0 * 262144, attb + 0 * 2304, gcb_b + 0 * 512, nullptr, nullptr, H, nullptr, 512);
        // L3: Y = Y + tanh(att3 @ (H @ W3) + b3)
        gemm3_kernel<512, 512, 1><<<g2, 256, 0, stream>>>(H, Wtb + 1 * 262144, attb + 1 * 2304, gcb_b + 1 * 512, Y, nullptr, Y, nullptr, 512);
        // L4: H = tanh(att4 @ (Y @ W4) + b4)
        gemm3_kernel<512, 512, 0><<<g2, 256, 0, stream>>>(Y, Wtb + 2 * 262144, attb + 2 * 2304, gcb_b + 2 * 512, nullptr, nullptr, H, nullptr, 512);
        // L5: Y = Y + tanh(att5 @ (H @ W5) + b5)
        gemm3_kernel<512, 512, 1><<<g2, 256, 0, stream>>>(H, Wtb + 3 * 262144, attb + 3 * 2304, gcb_b + 3 * 512, Y, nullptr, Y, nullptr, 512);
        // L6 (gc7): gcn_out = att7 @ (Y @ W7) + b7 + dct_in, N=10, fp32 out
        gemm3_kernel<512, 512, 2><<<g1, 256, 0, stream>>>(Y, Wt7p, att7, gc7_b, nullptr, dct_in, nullptr, gcn_out, 10);
        int n2 = Bc * 1440;
        recon_kernel<<<(n2 + 255) / 256, 256, 0, stream>>>(gcn_out, dctm, fusedb, Bc);
        ffc_kernel<<<Bc, 256, 0, stream>>>(seqc, ffc_wl, ffc_wg, fusedb);
        mlp_kernel<<<Bc, 256, 0, stream>>>(fusedb, mlp_w1, mlp_w2, outc);
    }
}

// Round 4
// 454.385 us; speedup vs baseline: 9.4058x; 1.0361x over previous
//
#include <hip/hip_runtime.h>
#include <math.h>

#define BB 1024
#define TT 50
#define FF 48
#define EXTN 60
#define NFREQ 31

typedef _Float16 h8 __attribute__((ext_vector_type(8)));
typedef _Float16 h4 __attribute__((ext_vector_type(4)));
typedef float f4 __attribute__((ext_vector_type(4)));

__device__ __forceinline__ float fast_tanh(float x) {
    float e = __expf(2.0f * x);
    return 1.0f - 2.0f * __builtin_amdgcn_rcpf(e + 1.0f);
}

// async global->LDS, 16B per lane. LDS dest = wave-uniform base + lane*16.
__device__ __forceinline__ void gl16(const void* g, void* l) {
#if __has_builtin(__builtin_amdgcn_global_load_lds)
    __builtin_amdgcn_global_load_lds(
        (const __attribute__((address_space(1))) void*)(uintptr_t)g,
        (__attribute__((address_space(3))) void*)(uint32_t)(uintptr_t)l,
        16, 0, 0);
#else
    int lane = threadIdx.x & 63;
    *(h8*)((char*)l + lane * 16) = *(const h8*)g;
#endif
}

// ---------------- fused prep: weight transpose/convert + att copies + DCT tables ----------------
// blocks [0,256): gcb transpose; [256,384): Wt1p; [384,416): Wt7p (16x512);
// [416,470): att copies (13824); [470,474): dctm+dtail.
__global__ void prep_kernel(const float* __restrict__ gcb_w, _Float16* __restrict__ Wtb,
                            const float* __restrict__ gc1_w, _Float16* __restrict__ Wt1p,
                            const float* __restrict__ gc7_w, _Float16* __restrict__ Wt7p,
                            const float* __restrict__ gc1_att, const float* __restrict__ gcb_att,
                            const float* __restrict__ gc7_att, _Float16* __restrict__ att_all,
                            float* __restrict__ dctm, float* __restrict__ dtail) {
    __shared__ _Float16 t[64][72];
    int blk = blockIdx.x, tid = threadIdx.x;
    if (blk < 256) {
        int z = blk >> 6, rem = blk & 63;
        int n0 = (rem & 7) * 64, k0 = (rem >> 3) * 64;
        const float* Ws = gcb_w + (size_t)z * 262144;
        _Float16* Wd = Wtb + (size_t)z * 262144;
        for (int i = tid; i < 4096; i += 256) {
            int r = i >> 6, c = i & 63;
            t[r][c] = (_Float16)Ws[(size_t)(k0 + r) * 512 + n0 + c];
        }
        __syncthreads();
        for (int i = tid; i < 4096; i += 256) {
            int r = i >> 6, c = i & 63;
            Wd[(size_t)(n0 + r) * 512 + k0 + c] = t[c][r];
        }
    } else if (blk < 384) {
        int idx = (blk - 256) * 256 + tid;
        int n = idx >> 6, k = idx & 63;
        Wt1p[idx] = (k < 10) ? (_Float16)gc1_w[k * 512 + n] : (_Float16)0.0f;
    } else if (blk < 416) {
        int idx = (blk - 384) * 256 + tid;
        if (idx < 8192) {
            int n = idx >> 9, k = idx & 511;
            Wt7p[idx] = (n < 10) ? (_Float16)gc7_w[k * 10 + n] : (_Float16)0.0f;
        }
    } else if (blk < 470) {
        int idx = (blk - 416) * 256 + tid;
        if (idx < 13824) {
            float v = (idx < 2304) ? gc1_att[idx]
                    : (idx < 11520) ? gcb_att[idx - 2304]
                                    : gc7_att[idx - 11520];
            att_all[idx] = (_Float16)v;
        }
    } else {
        int idx = (blk - 470) * 256 + tid;
        if (idx < 900) {
            int d = idx / 30, k = idx % 30;
            double w = (d == 0) ? sqrt(1.0 / 30.0) : sqrt(2.0 / 30.0);
            dctm[idx] = (float)(w * cos(M_PI * (k + 0.5) * d / 30.0));
        } else if (idx < 910) {
            int d = idx - 900;
            double w = (d == 0) ? sqrt(1.0 / 30.0) : sqrt(2.0 / 30.0);
            double s = 0.0;
            for (int k = 10; k < 30; ++k) s += w * cos(M_PI * (k + 0.5) * d / 30.0);
            dtail[d] = (float)s;
        }
    }
}

// ---------------- dct_in[b,f,d] = sum_k dctm[d,k]*gcn_in[k,f]; f16 copy padded to 64 ----------------
__global__ void dct_in_kernel(const float* __restrict__ seq, const float* __restrict__ dctm,
                              const float* __restrict__ dtail, float* __restrict__ dct_in,
                              _Float16* __restrict__ dct_in_h, int Bc) {
    int idx = blockIdx.x * blockDim.x + threadIdx.x;
    if (idx >= Bc * 3072) return;
    int b = idx / 3072, r = idx % 3072;
    int f = r >> 6, d = r & 63;
    float acc = 0.f;
    if (d < 10) {
        const float* s = seq + (size_t)b * TT * FF;
        acc = dtail[d] * s[49 * FF + f];
        #pragma unroll
        for (int k = 0; k < 10; ++k) acc += dctm[d * 30 + k] * s[(40 + k) * FF + f];
        dct_in[(size_t)b * 480 + f * 10 + d] = acc;
    }
    dct_in_h[idx] = (_Float16)acc;
}

// ---------------- fused MFMA gconv: out = [resid +] tanh( att @ (A @ W) + bias ) ----------
// Tile: M=96 (2 batches) x N=128, K-chunk 64, 256 threads (4 waves).
// MODE 0: tanh, f16 out. MODE 1: tanh + f16 resid, f16 out.
template<int KTOT, int LDA, int MODE>
__launch_bounds__(256, 4)
__global__ void gemm4_kernel(const _Float16* __restrict__ A,
                             const _Float16* __restrict__ Wt,
                             const _Float16* __restrict__ att_h,
                             const float* __restrict__ bias,
                             const _Float16* __restrict__ residh,
                             _Float16* __restrict__ outh) {
    __shared__ __align__(16) char smem[35584];
    char* As  = smem;               // 96 x 128 B  (swizzled blocks)
    char* Bs  = smem + 12288;       // 128 x 128 B (swizzled blocks)
    char* Cs  = smem;               // 128 x 144 B epilogue transit (aliases As+Bs)
    char* Ats = smem + 28672;       // 48 x 144 B att (k zero-padded to 64)

    const int tid  = threadIdx.x;
    const int lane = tid & 63, wv = tid >> 6;
    const int l16  = lane & 15, quad = lane >> 4;
    const int py   = blockIdx.y;
    const int c0   = blockIdx.x << 7;
    const _Float16 HZ = (_Float16)0.0f;

    // stage att (48 rows x 9 blocks of 16B, blocks >=6 zero)
    for (int v = tid; v < 432; v += 256) {
        int row = v / 9, b9 = v % 9;
        h8 val = (h8)HZ;
        if (b9 < 6) val = *(const h8*)(att_h + row * 48 + b9 * 8);
        *(h8*)(Ats + row * 144 + b9 * 16) = val;
    }

    // per-lane staging pointers (source-block XOR swizzle)
    const int lrow8 = lane >> 3;
    const int lblk  = (lane & 7) ^ lrow8;
    const char* aptr[3]; char* alds[3];
    #pragma unroll
    for (int j = 0; j < 3; ++j) {
        int row = (wv * 3 + j) * 8 + lrow8;                 // 0..95
        aptr[j] = (const char*)(A + (size_t)(py * 96 + row) * LDA + lblk * 8);
        alds[j] = As + (wv * 3 + j) * 1024;
    }
    const char* bptr[4]; char* blds[4];
    #pragma unroll
    for (int j = 0; j < 4; ++j) {
        int row = (wv * 4 + j) * 8 + lrow8;                 // 0..127
        bptr[j] = (const char*)(Wt + (size_t)(c0 + row) * KTOT + lblk * 8);
        blds[j] = Bs + (wv * 4 + j) * 1024;
    }

    f4 acc[6][2];
    #pragma unroll
    for (int r = 0; r < 6; ++r)
        #pragma unroll
        for (int ct = 0; ct < 2; ++ct) acc[r][ct] = (f4)0.0f;

    for (int k0 = 0; k0 < KTOT; k0 += 64) {
        #pragma unroll
        for (int j = 0; j < 3; ++j) { gl16(aptr[j], alds[j]); aptr[j] += 128; }
        #pragma unroll
        for (int j = 0; j < 4; ++j) { gl16(bptr[j], blds[j]); bptr[j] += 128; }
        __syncthreads();
        #pragma unroll
        for (int ks = 0; ks < 2; ++ks) {
            const int sw = (((ks * 4 + quad) ^ (l16 & 7)) << 4);
            h8 af[6], bf[2];
            #pragma unroll
            for (int r = 0; r < 6; ++r) af[r] = *(h8*)(As + (16 * r + l16) * 128 + sw);
            #pragma unroll
            for (int ct = 0; ct < 2; ++ct) bf[ct] = *(h8*)(Bs + (wv * 32 + ct * 16 + l16) * 128 + sw);
            #pragma unroll
            for (int r = 0; r < 6; ++r)
                #pragma unroll
                for (int ct = 0; ct < 2; ++ct)
                    acc[r][ct] = __builtin_amdgcn_mfma_f32_16x16x32_f16(af[r], bf[ct], acc[r][ct], 0, 0, 0);
        }
        __syncthreads();
    }

    // zero the k=48..63 pad of Cs (128 rows)
    if (tid < 128) {
        *(h8*)(Cs + tid * 144 + 96)  = (h8)HZ;
        *(h8*)(Cs + tid * 144 + 112) = (h8)HZ;
    }

    #pragma unroll
    for (int bb = 0; bb < 2; ++bb) {
        // write C_b (48 x 128) transposed to Cs[c][m] as f16
        #pragma unroll
        for (int r = 0; r < 3; ++r)
            #pragma unroll
            for (int ct = 0; ct < 2; ++ct) {
                h4 hv;
                #pragma unroll
                for (int i = 0; i < 4; ++i) hv[i] = (_Float16)acc[3 * bb + r][ct][i];
                int ccol = wv * 32 + ct * 16 + l16;
                *(h4*)(Cs + ccol * 144 + (16 * r + quad * 4) * 2) = hv;
            }
        __syncthreads();
        // mix: D2 = att @ C_b
        f4 acc2[3][2];
        #pragma unroll
        for (int r = 0; r < 3; ++r)
            #pragma unroll
            for (int ct = 0; ct < 2; ++ct) acc2[r][ct] = (f4)0.0f;
        #pragma unroll
        for (int ks = 0; ks < 2; ++ks) {
            const int ko = ks * 64 + quad * 16;
            h8 af2[3], bf2[2];
            #pragma unroll
            for (int r = 0; r < 3; ++r) af2[r] = *(h8*)(Ats + (16 * r + l16) * 144 + ko);
            #pragma unroll
            for (int ct = 0; ct < 2; ++ct) bf2[ct] = *(h8*)(Cs + (wv * 32 + ct * 16 + l16) * 144 + ko);
            #pragma unroll
            for (int r = 0; r < 3; ++r)
                #pragma unroll
                for (int ct = 0; ct < 2; ++ct)
                    acc2[r][ct] = __builtin_amdgcn_mfma_f32_16x16x32_f16(af2[r], bf2[ct], acc2[r][ct], 0, 0, 0);
        }
        const int b = py * 2 + bb;
        #pragma unroll
        for (int ct = 0; ct < 2; ++ct) {
            int gc = c0 + wv * 32 + ct * 16 + l16;
            float bv = bias[gc];
            #pragma unroll
            for (int r = 0; r < 3; ++r)
                #pragma unroll
                for (int i = 0; i < 4; ++i) {
                    int n = 16 * r + quad * 4 + i;
                    float v = fast_tanh(acc2[r][ct][i] + bv);
                    size_t o = ((size_t)b * 48 + n) * 512 + gc;
                    if (MODE == 1) v += (float)residh[o];
                    outh[o] = (_Float16)v;
                }
        }
        if (bb == 0) __syncthreads();
    }
}

// ---------------- L6 (gc7): gcn_out = att7 @ (Y @ W7) + b7 + dct_in, N=10, fp32 out ---------
// 1 wave per WG, M=96 (2 batches), N-tile 16 (cols >=10 are zero-padded weights).
__launch_bounds__(64)
__global__ void gemm_l6_kernel(const _Float16* __restrict__ A,      // (B,48,512)
                               const _Float16* __restrict__ Wt,     // (16,512) padded
                               const _Float16* __restrict__ att_h,
                               const float* __restrict__ bias,      // (10)
                               const float* __restrict__ resid32,
                               float* __restrict__ out32) {
    __shared__ __align__(16) char smem[21248];
    char* As  = smem;               // 96 x 128 B
    char* Bs  = smem + 12288;       // 16 x 128 B
    char* Ats = smem + 14336;       // 48 x 144 B
    char* Cs  = smem;               // 16 x 144 B (epilogue, aliases As)

    const int lane = threadIdx.x;
    const int l16  = lane & 15, quad = lane >> 4;
    const int py   = blockIdx.y;
    const _Float16 HZ = (_Float16)0.0f;

    for (int v = lane; v < 432; v += 64) {
        int row = v / 9, b9 = v % 9;
        h8 val = (h8)HZ;
        if (b9 < 6) val = *(const h8*)(att_h + row * 48 + b9 * 8);
        *(h8*)(Ats + row * 144 + b9 * 16) = val;
    }

    const int lrow8 = lane >> 3;
    const int lblk  = (lane & 7) ^ lrow8;
    const char* aptr[12]; const char* bptr[2];
    #pragma unroll
    for (int j = 0; j < 12; ++j)
        aptr[j] = (const char*)(A + (size_t)(py * 96 + j * 8 + lrow8) * 512 + lblk * 8);
    #pragma unroll
    for (int j = 0; j < 2; ++j)
        bptr[j] = (const char*)(Wt + (size_t)(j * 8 + lrow8) * 512 + lblk * 8);

    f4 acc[6];
    #pragma unroll
    for (int r = 0; r < 6; ++r) acc[r] = (f4)0.0f;

    for (int k0 = 0; k0 < 512; k0 += 64) {
        #pragma unroll
        for (int j = 0; j < 12; ++j) { gl16(aptr[j], As + j * 1024); aptr[j] += 128; }
        #pragma unroll
        for (int j = 0; j < 2; ++j)  { gl16(bptr[j], Bs + j * 1024); bptr[j] += 128; }
        __syncthreads();
        #pragma unroll
        for (int ks = 0; ks < 2; ++ks) {
            const int sw = (((ks * 4 + quad) ^ (l16 & 7)) << 4);
            h8 bf = *(h8*)(Bs + l16 * 128 + sw);
            #pragma unroll
            for (int r = 0; r < 6; ++r) {
                h8 af = *(h8*)(As + (16 * r + l16) * 128 + sw);
                acc[r] = __builtin_amdgcn_mfma_f32_16x16x32_f16(af, bf, acc[r], 0, 0, 0);
            }
        }
        __syncthreads();
    }

    if (lane < 16) {
        *(h8*)(Cs + lane * 144 + 96)  = (h8)HZ;
        *(h8*)(Cs + lane * 144 + 112) = (h8)HZ;
    }

    #pragma unroll
    for (int bb = 0; bb < 2; ++bb) {
        #pragma unroll
        for (int r = 0; r < 3; ++r) {
            h4 hv;
            #pragma unroll
            for (int i = 0; i < 4; ++i) hv[i] = (_Float16)acc[3 * bb + r][i];
            *(h4*)(Cs + l16 * 144 + (16 * r + quad * 4) * 2) = hv;
        }
        f4 acc2[3];
        #pragma unroll
        for (int r = 0; r < 3; ++r) acc2[r] = (f4)0.0f;
        #pragma unroll
        for (int ks = 0; ks < 2; ++ks) {
            const int ko = ks * 64 + quad * 16;
            h8 bf2 = *(h8*)(Cs + l16 * 144 + ko);
            #pragma unroll
            for (int r = 0; r < 3; ++r) {
                h8 af2 = *(h8*)(Ats + (16 * r + l16) * 144 + ko);
                acc2[r] = __builtin_amdgcn_mfma_f32_16x16x32_f16(af2, bf2, acc2[r], 0, 0, 0);
            }
        }
        const int b = py * 2 + bb;
        if (l16 < 10) {
            float bv = bias[l16];
            #pragma unroll
            for (int r = 0; r < 3; ++r)
                #pragma unroll
                for (int i = 0; i < 4; ++i) {
                    int n = 16 * r + quad * 4 + i;
                    size_t o = ((size_t)b * 48 + n) * 10 + l16;
                    out32[o] = acc2[r][i] + bv + resid32[o];
                }
        }
    }
}

// ---------------- recon[b,t,f] = sum_d dctm[d,t]*gcn_out[b,f,d] (idct = dctm^T) -------
__global__ void recon_kernel(const float* __restrict__ gcn_out, const float* __restrict__ dctm,
                             float* __restrict__ fused, int Bc) {
    int idx = blockIdx.x * blockDim.x + threadIdx.x;
    if (idx >= Bc * 1440) return;
    int b = idx / 1440, r = idx % 1440;
    int f = r / 30, t = r % 30;
    const float* g = gcn_out + ((size_t)b * 48 + f) * 10;
    float s = 0.f;
    #pragma unroll
    for (int d = 0; d < 10; ++d) s += dctm[d * 30 + t] * g[d];
    fused[(size_t)b * 1920 + f * 40 + t] = s;
}

// ---------------- FFC branch (direct DFT; only first 10 irfft samples needed) --------
__launch_bounds__(256)
__global__ void ffc_kernel(const float* __restrict__ seq, const float* __restrict__ wl,
                           const float* __restrict__ wg, float* __restrict__ fused) {
    int b = blockIdx.x, tid = threadIdx.x;
    __shared__ float ext[EXTN][FF];
    __shared__ float Xre[FF][32];
    __shared__ float Xim[FF][32];
    __shared__ float Yo[6][16][32];
    __shared__ float c60[60], s60[60];
    __shared__ float wls[9], wgs[36];
    const float* s = seq + (size_t)b * TT * FF;
    for (int idx = tid; idx < EXTN * FF; idx += 256) {
        int t = idx / FF, f = idx % FF;
        int ts = t < TT ? t : TT - 1;
        ext[t][f] = s[ts * FF + f];
    }
    if (tid < 60) { c60[tid] = cospif(tid / 30.0f); s60[tid] = sinpif(tid / 30.0f); }
    if (tid >= 64 && tid < 73) wls[tid - 64] = wl[tid - 64];
    if (tid >= 128 && tid < 164) wgs[tid - 128] = wg[tid - 128];
    __syncthreads();
    for (int idx = tid; idx < FF * NFREQ; idx += 256) {
        int f = idx % FF, k = idx / FF;
        float re = 0.f, im = 0.f;
        int kt = 0;
        for (int t = 0; t < EXTN; ++t) {
            float v = ext[t][f];
            re += v * c60[kt];
            im -= v * s60[kt];
            kt += k; kt = (kt >= 60) ? kt - 60 : kt;
        }
        Xre[f][k] = re; Xim[f][k] = im;
    }
    __syncthreads();
    for (int idx = tid; idx < 6 * 16 * NFREQ; idx += 256) {
        int k = idx % NFREQ; int g = (idx / NFREQ) % 16; int o = idx / (NFREQ * 16);
        float v = wgs[o * 6 + 0] * Xre[g][k]      + wgs[o * 6 + 1] * Xre[16 + g][k]
                + wgs[o * 6 + 2] * Xre[32 + g][k] + wgs[o * 6 + 3] * Xim[g][k]
                + wgs[o * 6 + 4] * Xim[16 + g][k] + wgs[o * 6 + 5] * Xim[32 + g][k];
        Yo[o][g][k] = fmaxf(v, 0.f);
    }
    __syncthreads();
    for (int idx = tid; idx < 480; idx += 256) {
        int t = idx % 10; int g = (idx / 10) % 16; int c = idx / 160;
        float acc = Yo[c][g][0] + Yo[c][g][30] * ((t & 1) ? -1.f : 1.f);
        float s2 = 0.f;
        int kt = t;
        for (int k = 1; k < 30; ++k) {
            s2 += Yo[c][g][k] * c60[kt] - Yo[c + 3][g][k] * s60[kt];
            kt += t; kt = (kt >= 60) ? kt - 60 : kt;
        }
        acc = (acc + 2.f * s2) * (1.0f / 60.0f);
        float loc = wls[c * 3 + 0] * ext[t][g] + wls[c * 3 + 1] * ext[t][16 + g]
                  + wls[c * 3 + 2] * ext[t][32 + g];
        int f = c * 16 + g;
        fused[(size_t)b * 1920 + f * 40 + 30 + t] = acc + loc;
    }
}

// ---------------- MLP head (only first 10 of 40 output rows needed) ----------------
__launch_bounds__(256)
__global__ void mlp_kernel(const float* __restrict__ fused, const float* __restrict__ w1,
                           const float* __restrict__ w2, float* __restrict__ out) {
    int b = blockIdx.x, tid = threadIdx.x;
    __shared__ float fs[48][40];
    __shared__ float hs[48][257];
    for (int idx = tid; idx < 1920; idx += 256) fs[idx / 40][idx % 40] = fused[(size_t)b * 1920 + idx];
    __syncthreads();
    for (int idx = tid; idx < 48 * 256; idx += 256) {
        int o = idx & 255, f = idx >> 8;
        const float* wr = w1 + o * 40;
        float s = 0.f;
        #pragma unroll
        for (int t = 0; t < 40; ++t) s += fs[f][t] * wr[t];
        hs[f][o] = fmaxf(s, 0.f);
    }
    __syncthreads();
    for (int idx = tid; idx < 480; idx += 256) {
        int f = idx % 48, t = idx / 48;
        const float* wr = w2 + t * 256;
        float s = 0.f;
        for (int o = 0; o < 256; ++o) s += hs[f][o] * wr[o];
        out[(size_t)b * 480 + t * 48 + f] = s;
    }
}

extern "C" void kernel_launch(void* const* d_in, const int* in_sizes, int n_in,
                              void* d_out, int out_size, void* d_ws, size_t ws_size,
                              hipStream_t stream) {
    (void)in_sizes; (void)n_in; (void)out_size;
    const float* seq     = (const float*)d_in[0];
    // d_in[1..4] = wq1,wq2,wk1,wk2 — dead (attention branch sliced away by combined[:,:,:10])
    const float* gc1_w   = (const float*)d_in[5];
    const float* gc1_att = (const float*)d_in[6];
    const float* gc1_b   = (const float*)d_in[7];
    const float* gcb_w   = (const float*)d_in[8];
    const float* gcb_att = (const float*)d_in[9];
    const float* gcb_b   = (const float*)d_in[10];
    const float* gc7_w   = (const float*)d_in[11];
    const float* gc7_att = (const float*)d_in[12];
    const float* gc7_b   = (const float*)d_in[13];
    const float* mlp_w1  = (const float*)d_in[14];
    const float* mlp_w2  = (const float*)d_in[15];
    const float* ffc_wl  = (const float*)d_in[16];
    const float* ffc_wg  = (const float*)d_in[17];
    float* out = (float*)d_out;
    char* ws = (char*)d_ws;

    // fixed region
    float*    dctm  = (float*)ws;                        // 900 f
    float*    dtail = dctm + 900;                        // 10 f
    char*     p0    = ws + 4096;
    _Float16* Wtb   = (_Float16*)p0;           p0 += 4 * 262144 * 2;   // 4 x (512,512)
    _Float16* Wt1p  = (_Float16*)p0;           p0 += 32768 * 2;        // (512,64) zero-padded
    _Float16* Wt7p  = (_Float16*)p0;           p0 += 8192 * 2;         // (16,512) zero-padded
    _Float16* att1  = (_Float16*)p0;           p0 += 2304 * 2;
    _Float16* attb  = (_Float16*)p0;           p0 += 4 * 2304 * 2;
    _Float16* att7  = (_Float16*)p0;           p0 += 2304 * 2;
    const size_t fixed_bytes = (size_t)(p0 - ws);

    // per-batch scratch bytes: dct_in 1920 + gcn_out 1920 + fused 7680 + dct_in_h 6144 + Y 49152 + H 49152
    const size_t per_batch = 115968;
    size_t avail = (ws_size > fixed_bytes) ? (ws_size - fixed_bytes) : 0;
    int nc = 1;
    while ((size_t)(BB / nc) * per_batch > avail && nc < 64) nc *= 2;
    int Bc = BB / nc;

    char* p = ws + fixed_bytes;
    float*    dct_in   = (float*)p;                 p += (size_t)Bc * 1920;
    float*    gcn_out  = (float*)p;                 p += (size_t)Bc * 1920;
    float*    fusedb   = (float*)p;                 p += (size_t)Bc * 7680;
    _Float16* dct_in_h = (_Float16*)p;              p += (size_t)Bc * 6144;
    _Float16* Y        = (_Float16*)p;              p += (size_t)Bc * 49152;
    _Float16* H        = (_Float16*)p;

    prep_kernel<<<474, 256, 0, stream>>>(gcb_w, Wtb, gc1_w, Wt1p, gc7_w, Wt7p,
                                         gc1_att, gcb_att, gc7_att, att1, dctm, dtail);

    for (int ci = 0; ci < nc; ++ci) {
        const float* seqc = seq + (size_t)ci * Bc * TT * FF;
        float* outc = out + (size_t)ci * Bc * 480;
        int n1 = Bc * 3072;
        dct_in_kernel<<<(n1 + 255) / 256, 256, 0, stream>>>(seqc, dctm, dtail, dct_in, dct_in_h, Bc);
        dim3 g4(4, Bc / 2), gl6(1, Bc / 2);
        // L1: Y = tanh(att1 @ (dct_in @ W1) + b1), K padded to 64
        gemm4_kernel<64, 64, 0><<<g4, 256, 0, stream>>>(dct_in_h, Wt1p, att1, gc1_b, nullptr, Y);
        // L2: H = tanh(att2 @ (Y @ W2) + b2)
        gemm4_kernel<512, 512, 0><<<g4, 256, 0, stream>>>(Y, Wtb + 0 * 262144, attb + 0 * 2304, gcb_b + 0 * 512, nullptr, H);
        // L3: Y = Y + tanh(att3 @ (H @ W3) + b3)
        gemm4_kernel<512, 512, 1><<<g4, 256, 0, stream>>>(H, Wtb + 1 * 262144, attb + 1 * 2304, gcb_b + 1 * 512, Y, Y);
        // L4: H = tanh(att4 @ (Y @ W4) + b4)
        gemm4_kernel<512, 512, 0><<<g4, 256, 0, stream>>>(Y, Wtb + 2 * 262144, attb + 2 * 2304, gcb_b + 2 * 512, nullptr, H);
        // L5: Y = Y + tanh(att5 @ (H @ W5) + b5)
        gemm4_kernel<512, 512, 1><<<g4, 256, 0, stream>>>(H, Wtb + 3 * 262144, attb + 3 * 2304, gcb_b + 3 * 512, Y, Y);
        // L6 (gc7): gcn_out = att7 @ (Y @ W7) + b7 + dct_in
        gemm_l6_kernel<<<gl6, 64, 0, stream>>>(Y, Wt7p, att7, gc7_b, dct_in, gcn_out);
        int n2 = Bc * 1440;
        recon_kernel<<<(n2 + 255) / 256, 256, 0, stream>>>(gcn_out, dctm, fusedb, Bc);
        ffc_kernel<<<Bc, 256, 0, stream>>>(seqc, ffc_wl, ffc_wg, fusedb);
        mlp_kernel<<<Bc, 256, 0, stream>>>(fusedb, mlp_w1, mlp_w2, outc);
    }
}